// Round 4
// baseline (253.566 us; speedup 1.0000x reference)
//
#include <hip/hip_runtime.h>
#include <hip/hip_cooperative_groups.h>

namespace cg = cooperative_groups;

#define D 4096
#define H 512
#define NCH 64
#define CCH 64
#define B 8

typedef __bf16 bf16x8 __attribute__((ext_vector_type(8)));
typedef float  f32x4  __attribute__((ext_vector_type(4)));

// workspace layout (float offsets)
#define OFF_P    0                         // P_nh[n][h]           32768
#define OFF_PHN  (OFF_P + NCH*H)           // P_hn[h][n]           32768
#define OFF_UPT  (OFF_PHN + H*NCH)         // up_t[b][h][n]        262144
#define OFF_S    (OFF_UPT + B*H*NCH)       // s[b][h]              4096
#define OFF_ST2  (OFF_S + B*H)             // -2*t*s[b][h]         4096
#define OFF_Q    (OFF_ST2 + B*H)           // q[b][h]              4096
#define OFF_C    (OFF_Q + B*H)             // c[h]                 512
#define OFF_VN   (OFF_C + H)               // ||v_b||+1e-6         64 (pad)
#define OFF_A1   (OFF_VN + 64)             // a1[b][n*64+i]        32768
#define OFF_ZB   (OFF_A1 + B*NCH*CCH)      // zblk[b][i][n*64+k]   2097152
#define OFF_W1H  (OFF_ZB + B*64*4096)      // W1hi bf16 [d][h]
#define OFF_W1L  (OFF_W1H + (D*H)/2)       // W1lo bf16 [d][h]
#define OFF_WH   (OFF_W1L + (D*H)/2)       // whi bf16 [b][n][h]
#define OFF_WL   (OFF_WH + (B*NCH*H)/2)    // wlo bf16 [b][n][h]

__device__ __forceinline__ unsigned short f2bf(float x) {
    unsigned int u = __float_as_uint(x);
    unsigned int r = (u + 0x7FFFu + ((u >> 16) & 1u)) >> 16;   // RNE
    return (unsigned short)r;
}
__device__ __forceinline__ float bf2f(unsigned short s) {
    return __uint_as_float(((unsigned int)s) << 16);
}

__global__ __launch_bounds__(512, 2)
void fused(const float* __restrict__ W1, const float* __restrict__ state,
           const float* __restrict__ x0, const float* __restrict__ x1,
           const float* __restrict__ tptr, const float* __restrict__ W2,
           float* __restrict__ ws, float* __restrict__ out) {
    cg::grid_group grid = cg::this_grid();
    int bid = blockIdx.x;   // 0..255
    int tid = threadIdx.x;  // 0..511

    __shared__ union {
        struct { float xs[B][64]; f32x4 red[8][32][9]; } p1;
        struct { float lm[8][8]; float ms[8]; float lv[8]; } p2;
        struct { float gp[2][2][64][67]; float coefs[2][64]; } p4;
    } sh;

    unsigned short* __restrict__ W1Hp = (unsigned short*)(ws + OFF_W1H);
    unsigned short* __restrict__ W1Lp = (unsigned short*)(ws + OFF_W1L);
    unsigned short* __restrict__ WHp  = (unsigned short*)(ws + OFF_WH);
    unsigned short* __restrict__ WLp  = (unsigned short*)(ws + OFF_WL);

    // ---------------- P1: W1 reduce + bf16 split (block = (n, h-quarter)) ----
    {
        int n = bid >> 2, ht = bid & 3;
        float ts = tptr[0];
        float window = 4.f * ts * (1.f - ts);
        if (tid < 64) {
            int d = n * 64 + tid;
            for (int b = 0; b < B; ++b) {
                float a0 = x0[b * D + d];
                float a1v = x1[b * D + d];
                float dev = state[b * D + d];
                sh.p1.xs[b][tid] = a0 + ts * (a1v - a0) + window * dev;
            }
        }
        __syncthreads();

        if (tid < 256) {
            int hq = ht * 32 + (tid & 31);
            int jh = tid >> 5;
            f32x4 p4v = {0.f, 0.f, 0.f, 0.f};
            f32x4 up[B];
#pragma unroll
            for (int b = 0; b < B; ++b) up[b] = p4v;
#pragma unroll
            for (int jj = 0; jj < 8; ++jj) {
                int j = jh * 8 + jj;
                int d = n * 64 + j;
                f32x4 w = ((const f32x4*)W1)[d * (H / 4) + hq];
                p4v += w;
#pragma unroll
                for (int b = 0; b < B; ++b) up[b] += w * sh.p1.xs[b][j];
                unsigned short h0 = f2bf(w.x), h1 = f2bf(w.y), h2 = f2bf(w.z), h3 = f2bf(w.w);
                ushort4 hv = {h0, h1, h2, h3};
                ushort4 lv = {f2bf(w.x - bf2f(h0)), f2bf(w.y - bf2f(h1)),
                              f2bf(w.z - bf2f(h2)), f2bf(w.w - bf2f(h3))};
                *(ushort4*)(W1Hp + d * H + hq * 4) = hv;
                *(ushort4*)(W1Lp + d * H + hq * 4) = lv;
            }
            int l = tid & 31;
            sh.p1.red[jh][l][0] = p4v;
#pragma unroll
            for (int b = 0; b < B; ++b) sh.p1.red[jh][l][1 + b] = up[b];
        }
        __syncthreads();

        if (tid < 32) {
            int l = tid;
            int hq = ht * 32 + l;
            f32x4 pt = sh.p1.red[0][l][0];
            f32x4 ut[B];
#pragma unroll
            for (int b = 0; b < B; ++b) ut[b] = sh.p1.red[0][l][1 + b];
            for (int g = 1; g < 8; ++g) {
                pt += sh.p1.red[g][l][0];
#pragma unroll
                for (int b = 0; b < B; ++b) ut[b] += sh.p1.red[g][l][1 + b];
            }
            *(f32x4*)(ws + OFF_P + n * H + hq * 4) = pt;
#pragma unroll
            for (int e = 0; e < 4; ++e) ws[OFF_PHN + (hq * 4 + e) * NCH + n] = pt[e];
#pragma unroll
            for (int b = 0; b < B; ++b)
#pragma unroll
                for (int e = 0; e < 4; ++e)
                    ws[OFF_UPT + (b * H + hq * 4 + e) * NCH + n] = ut[b][e];
        }
    }
    grid.sync();

    // ---------------- P2: per-sample scalars (blocks 0..7) -------------------
    if (bid < 8) {
        int b = bid;
        int wid = tid >> 6, lane = tid & 63;
        int h = tid;
        f32x4 u4 = {0.f, 0.f, 0.f, 0.f}, c4 = u4;
        const f32x4* upp = (const f32x4*)(ws + OFF_UPT + (b * H + h) * NCH);
        const f32x4* pp  = (const f32x4*)(ws + OFF_PHN + h * NCH);
#pragma unroll
        for (int j = 0; j < 16; ++j) { u4 += upp[j]; c4 += pp[j]; }
        float u = u4.x + u4.y + u4.z + u4.w;
        float c = c4.x + c4.y + c4.z + c4.w;

        float tt  = tanhf(u);
        float s   = 1.f - tt * tt;
        float st2 = -2.f * tt * s;
        ws[OFF_S   + b * H + h] = s;
        ws[OFF_ST2 + b * H + h] = st2;
        ws[OFF_C   + h] = c;

        const float4* w2p = (const float4*)(W2 + h * 8);
        float4 w2a = w2p[0], w2b = w2p[1];
        float w2r[8] = {w2a.x, w2a.y, w2a.z, w2a.w, w2b.x, w2b.y, w2b.z, w2b.w};

        float cs = c * s;
        float pr[8];
#pragma unroll
        for (int o = 0; o < 8; ++o) pr[o] = cs * w2r[o];
#pragma unroll
        for (int mk = 1; mk < 64; mk <<= 1)
#pragma unroll
            for (int o = 0; o < 8; ++o) pr[o] += __shfl_xor(pr[o], mk);
        if (lane == 0)
#pragma unroll
            for (int o = 0; o < 8; ++o) sh.p2.lm[wid][o] = pr[o];

        float v2 = 0.f;
        const float* v = state + (size_t)(B + b) * D;
#pragma unroll
        for (int j = 0; j < D / H; ++j) { float vv = v[j * H + h]; v2 += vv * vv; }
#pragma unroll
        for (int mk = 1; mk < 64; mk <<= 1) v2 += __shfl_xor(v2, mk);
        if (lane == 0) sh.p2.lv[wid] = v2;
        __syncthreads();

        if (tid < 8) {
            float a = 0.f;
            for (int w = 0; w < 8; ++w) a += sh.p2.lm[w][tid];
            sh.p2.ms[tid] = a;
        }
        if (tid == 0) {
            float a = 0.f;
            for (int w = 0; w < 8; ++w) a += sh.p2.lv[w];
            ws[OFF_VN + b] = sqrtf(a) + 1e-6f;
        }
        __syncthreads();

        float q = 0.f;
#pragma unroll
        for (int o = 0; o < 8; ++o) q += w2r[o] * sh.p2.ms[o];
        ws[OFF_Q + b * H + h] = q;
    }
    grid.sync();

    // ---------------- P3: w = st2*(P*q + c*r) -> bf16 hi/lo (one wave/unit) --
    {
        int gw = bid * 8 + (tid >> 6);
        if (gw < 512) {
            int n = gw >> 3, b = gw & 7;
            int lane = tid & 63;
            float M[8];
#pragma unroll
            for (int o = 0; o < 8; ++o) M[o] = 0.f;
            for (int j = 0; j < 8; ++j) {
                int h = j * 64 + lane;
                float ps = ws[OFF_P + n * H + h] * ws[OFF_S + b * H + h];
                const float4* wp = (const float4*)(W2 + h * 8);
                float4 wa = wp[0], wb = wp[1];
                M[0] += ps * wa.x; M[1] += ps * wa.y; M[2] += ps * wa.z; M[3] += ps * wa.w;
                M[4] += ps * wb.x; M[5] += ps * wb.y; M[6] += ps * wb.z; M[7] += ps * wb.w;
            }
#pragma unroll
            for (int mk = 1; mk < 64; mk <<= 1)
#pragma unroll
                for (int o = 0; o < 8; ++o) M[o] += __shfl_xor(M[o], mk);

            for (int j = 0; j < 8; ++j) {
                int h = j * 64 + lane;
                const float4* wp = (const float4*)(W2 + h * 8);
                float4 wa = wp[0], wb = wp[1];
                float r = wa.x*M[0] + wa.y*M[1] + wa.z*M[2] + wa.w*M[3]
                        + wb.x*M[4] + wb.y*M[5] + wb.z*M[6] + wb.w*M[7];
                float P = ws[OFF_P + n * H + h];
                float wv = ws[OFF_ST2 + b * H + h] * (P * ws[OFF_Q + b * H + h] + ws[OFF_C + h] * r);
                unsigned short hi = f2bf(wv);
                WHp[(b * NCH + n) * H + h] = hi;
                WLp[(b * NCH + n) * H + h] = f2bf(wv - bf2f(hi));
            }
        }
    }
    grid.sync();

    // ---------------- P4: MFMA GEMM + fused epilogue (2 units per block) -----
    {
        int g    = tid >> 8;          // group 0/1
        int gt   = tid & 255;         // tid within group
        int u    = bid * 2 + g;       // unit id
        int i    = u >> 3, b = u & 7; // both groups share i -> shared W1 reads
        int w2   = gt >> 6;           // wave within group
        int lane = tid & 63;
        int r16  = lane & 15;
        int kgrp = (lane >> 4) * 8;

        f32x4 acc[4][4];
        f32x4 zz = {0.f, 0.f, 0.f, 0.f};
#pragma unroll
        for (int m = 0; m < 4; ++m)
#pragma unroll
            for (int c = 0; c < 4; ++c) acc[m][c] = zz;

        int kb = w2 * 128 + kgrp;
        int baseA = (b * 64 + r16) * H;
        int baseB = (i * 64 + r16) * H;

        bf16x8 fa[2][8], fb[2][8];
#define LOADF(BUF, KOFS) do {                                              \
        int k_ = (KOFS);                                                   \
        _Pragma("unroll")                                                  \
        for (int m_ = 0; m_ < 4; ++m_) {                                   \
            int oA = baseA + m_ * 16 * H + k_;                             \
            fa[BUF][m_]     = *(const bf16x8*)(WHp + oA);                  \
            fa[BUF][4 + m_] = *(const bf16x8*)(WLp + oA);                  \
            int oB = baseB + m_ * 16 * H + k_;                             \
            fb[BUF][m_]     = *(const bf16x8*)(W1Hp + oB);                 \
            fb[BUF][4 + m_] = *(const bf16x8*)(W1Lp + oB);                 \
        } } while (0)

        LOADF(0, kb);
#pragma unroll
        for (int ks = 0; ks < 4; ++ks) {
            int cur = ks & 1;
            if (ks < 3) {
                if (cur == 0) LOADF(1, kb + (ks + 1) * 32);
                else          LOADF(0, kb + (ks + 1) * 32);
            }
#pragma unroll
            for (int m = 0; m < 4; ++m)
#pragma unroll
                for (int c = 0; c < 4; ++c) {
                    acc[m][c] = __builtin_amdgcn_mfma_f32_16x16x32_bf16(fa[cur][m], fb[cur][c], acc[m][c], 0, 0, 0);
                    acc[m][c] = __builtin_amdgcn_mfma_f32_16x16x32_bf16(fa[cur][m], fb[cur][4 + c], acc[m][c], 0, 0, 0);
                    acc[m][c] = __builtin_amdgcn_mfma_f32_16x16x32_bf16(fa[cur][4 + m], fb[cur][c], acc[m][c], 0, 0, 0);
                }
        }
#undef LOADF

        // cross-wave K reduction within group
        int rowb = (lane >> 4) * 4;
        if (w2 < 2) {
            float (*gpp)[67] = sh.p4.gp[g][w2];
#pragma unroll
            for (int m = 0; m < 4; ++m)
#pragma unroll
                for (int c = 0; c < 4; ++c)
#pragma unroll
                    for (int e = 0; e < 4; ++e)
                        gpp[m * 16 + rowb + e][c * 16 + r16] = acc[m][c][e];
        }
        __syncthreads();
        if (w2 >= 2) {
            float (*gpp)[67] = sh.p4.gp[g][w2 - 2];
#pragma unroll
            for (int m = 0; m < 4; ++m)
#pragma unroll
                for (int c = 0; c < 4; ++c)
#pragma unroll
                    for (int e = 0; e < 4; ++e)
                        gpp[m * 16 + rowb + e][c * 16 + r16] += acc[m][c][e];
        }
        __syncthreads();

        const float* v = state + (size_t)(B + b) * D;
        if (gt < 64) {
            int n = gt;
            float ss = 0.f, y = 0.f;
#pragma unroll 8
            for (int k = 0; k < 64; ++k) {
                float gv = sh.p4.gp[g][0][n][k] + sh.p4.gp[g][1][n][k];
                ss += gv * gv;
                y  += gv * v[n * 64 + k];
            }
            float nrm = sqrtf(ss) + 1e-6f;
            ws[OFF_A1 + (size_t)(b * NCH + n) * CCH + i] = y / nrm;
            sh.p4.coefs[g][n] = v[n * 64 + i] / nrm;
        }
        __syncthreads();

        float* zb = ws + OFF_ZB + ((size_t)b * 64 + i) * 4096;
#pragma unroll
        for (int r = 0; r < 16; ++r) {
            int idx = gt + r * 256;
            int n = idx >> 6, k = idx & 63;
            zb[idx] = (sh.p4.gp[g][0][n][k] + sh.p4.gp[g][1][n][k]) * sh.p4.coefs[g][n];
        }
    }
    grid.sync();

    // ---------------- P5: z reduction over i + final assembly ----------------
    if (bid < 64) {
        int idx = bid * 512 + tid;    // 0..32767
        float vel = state[32768 + idx];
        out[idx] = vel;
        int b = idx >> 12, e = idx & 4095;
        const float* zb = ws + OFF_ZB + (size_t)b * 64 * 4096 + e;
        float z = 0.f;
#pragma unroll 8
        for (int i = 0; i < 64; ++i) z += zb[(size_t)i * 4096];
        float a1 = ws[OFF_A1 + (size_t)b * 4096 + e];
        float av = -0.5f * vel * (a1 + z) / ws[OFF_VN + b];
        out[32768 + idx] = av - 0.1f * state[idx];
    }
}

extern "C" void kernel_launch(void* const* d_in, const int* in_sizes, int n_in,
                              void* d_out, int out_size, void* d_ws, size_t ws_size,
                              hipStream_t stream) {
    const float* t   = (const float*)d_in[0];
    const float* st  = (const float*)d_in[1];
    const float* x0  = (const float*)d_in[2];
    const float* x1  = (const float*)d_in[3];
    const float* W1  = (const float*)d_in[4];
    const float* W2  = (const float*)d_in[5];
    float* out = (float*)d_out;
    float* ws  = (float*)d_ws;

    void* args[] = {(void*)&W1, (void*)&st, (void*)&x0, (void*)&x1,
                    (void*)&t, (void*)&W2, (void*)&ws, (void*)&out};
    hipLaunchCooperativeKernel((const void*)fused, dim3(256), dim3(512),
                               args, 0, stream);
}

// Round 5
// 153.013 us; speedup vs baseline: 1.6572x; 1.6572x over previous
//
#include <hip/hip_runtime.h>

#define D 4096
#define H 512
#define NCH 64
#define CCH 64
#define B 8

typedef __bf16 bf16x8 __attribute__((ext_vector_type(8)));
typedef float  f32x4  __attribute__((ext_vector_type(4)));

// workspace layout (float offsets)
#define OFF_P    0                         // P_nh[n][h]           32768
#define OFF_PHN  (OFF_P + NCH*H)           // P_hn[h][n]           32768
#define OFF_UPT  (OFF_PHN + H*NCH)         // up_t[b][h][n]        262144
#define OFF_VN   (OFF_UPT + B*H*NCH)       // ||v_b||+1e-6         64 (pad)
#define OFF_A1   (OFF_VN + 64)             // a1[b][n*64+i]        32768
#define OFF_ZB   (OFF_A1 + B*NCH*CCH)      // zblk[b][i][n*64+k]   2097152
#define OFF_W1H  (OFF_ZB + B*64*4096)      // W1hi bf16 [d][h]
#define OFF_W1L  (OFF_W1H + (D*H)/2)       // W1lo bf16 [d][h]
#define OFF_WH   (OFF_W1L + (D*H)/2)       // whi bf16 [b][n][h]
#define OFF_WL   (OFF_WH + (B*NCH*H)/2)    // wlo bf16 [b][n][h]

__device__ __forceinline__ unsigned short f2bf(float x) {
    unsigned int u = __float_as_uint(x);
    unsigned int r = (u + 0x7FFFu + ((u >> 16) & 1u)) >> 16;   // RNE
    return (unsigned short)r;
}
__device__ __forceinline__ float bf2f(unsigned short s) {
    return __uint_as_float(((unsigned int)s) << 16);
}

// K1: per (n-chunk, h-quarter): float4 over h, j split 8 ways across threads.
// Produces: W1 bf16 hi/lo, P in both layouts, up_t[b][h][n].
__global__ __launch_bounds__(256) void k1_reduce_w1(const float* __restrict__ W1,
                                                    const float* __restrict__ state,
                                                    const float* __restrict__ x0,
                                                    const float* __restrict__ x1,
                                                    const float* __restrict__ tptr,
                                                    float* __restrict__ ws) {
    int n   = blockIdx.x;              // 0..63
    int ht  = blockIdx.y;              // 0..3
    int tid = threadIdx.x;             // 0..255
    int hq  = ht * 32 + (tid & 31);    // float4 group of h: 0..127
    int jh  = tid >> 5;                // 0..7 (j-eighth)

    __shared__ float xs[B][64];
    __shared__ f32x4 red[8][32][9];    // [jh][lane][p,up0..up7]

    float ts = tptr[0];
    float window = 4.f * ts * (1.f - ts);
    if (tid < 64) {
        int d = n * 64 + tid;
        for (int b = 0; b < B; ++b) {
            float a0 = x0[b * D + d];
            float a1v = x1[b * D + d];
            float dev = state[b * D + d];
            xs[b][tid] = a0 + ts * (a1v - a0) + window * dev;
        }
    }
    __syncthreads();

    unsigned short* __restrict__ W1Hp = (unsigned short*)(ws + OFF_W1H);
    unsigned short* __restrict__ W1Lp = (unsigned short*)(ws + OFF_W1L);

    f32x4 p4 = {0.f, 0.f, 0.f, 0.f};
    f32x4 up[B];
#pragma unroll
    for (int b = 0; b < B; ++b) up[b] = p4;

#pragma unroll
    for (int jj = 0; jj < 8; ++jj) {
        int j = jh * 8 + jj;
        int d = n * 64 + j;
        f32x4 w = ((const f32x4*)W1)[d * (H / 4) + hq];
        p4 += w;
#pragma unroll
        for (int b = 0; b < B; ++b) up[b] += w * xs[b][j];
        unsigned short h0 = f2bf(w.x), h1 = f2bf(w.y), h2 = f2bf(w.z), h3 = f2bf(w.w);
        ushort4 hv = {h0, h1, h2, h3};
        ushort4 lv = {f2bf(w.x - bf2f(h0)), f2bf(w.y - bf2f(h1)),
                      f2bf(w.z - bf2f(h2)), f2bf(w.w - bf2f(h3))};
        *(ushort4*)(W1Hp + d * H + hq * 4) = hv;
        *(ushort4*)(W1Lp + d * H + hq * 4) = lv;
    }

    int l = tid & 31;
    red[jh][l][0] = p4;
#pragma unroll
    for (int b = 0; b < B; ++b) red[jh][l][1 + b] = up[b];
    __syncthreads();

    if (jh == 0) {
        f32x4 pt = red[0][l][0];
        f32x4 ut[B];
#pragma unroll
        for (int b = 0; b < B; ++b) ut[b] = red[0][l][1 + b];
        for (int g = 1; g < 8; ++g) {
            pt += red[g][l][0];
#pragma unroll
            for (int b = 0; b < B; ++b) ut[b] += red[g][l][1 + b];
        }
        *(f32x4*)(ws + OFF_P + n * H + hq * 4) = pt;
#pragma unroll
        for (int e = 0; e < 4; ++e) ws[OFF_PHN + (hq * 4 + e) * NCH + n] = pt[e];
#pragma unroll
        for (int b = 0; b < B; ++b)
#pragma unroll
            for (int e = 0; e < 4; ++e)
                ws[OFF_UPT + (b * H + hq * 4 + e) * NCH + n] = ut[b][e];
    }
}

// K23: per-sample block (8 blocks x 512): phase A = s,st2,c,q,||v|| (kept in LDS);
// phase B = per (n,b) wave: M-reduce, r, w -> bf16 hi/lo.
__global__ __launch_bounds__(512) void k23(const float* __restrict__ W2,
                                           const float* __restrict__ state,
                                           float* __restrict__ ws) {
    int b = blockIdx.x, tid = threadIdx.x;
    int wid = tid >> 6, lane = tid & 63;

    __shared__ float sS[512], sS2[512], sC[512], sQ[512];
    __shared__ float lm[8][8];
    __shared__ float ms[8];
    __shared__ float lv[8];

    // ---- phase A ----
    int h = tid;
    f32x4 u4 = {0.f, 0.f, 0.f, 0.f}, c4 = u4;
    const f32x4* upp = (const f32x4*)(ws + OFF_UPT + (b * H + h) * NCH);
    const f32x4* pp  = (const f32x4*)(ws + OFF_PHN + h * NCH);
#pragma unroll
    for (int j = 0; j < 16; ++j) { u4 += upp[j]; c4 += pp[j]; }
    float u = u4.x + u4.y + u4.z + u4.w;
    float c = c4.x + c4.y + c4.z + c4.w;

    float tt  = tanhf(u);
    float s   = 1.f - tt * tt;
    float st2 = -2.f * tt * s;
    sS[h] = s; sS2[h] = st2; sC[h] = c;

    const float4* w2p = (const float4*)(W2 + h * 8);
    float4 w2a = w2p[0], w2b = w2p[1];
    float w2r[8] = {w2a.x, w2a.y, w2a.z, w2a.w, w2b.x, w2b.y, w2b.z, w2b.w};

    float cs = c * s;
    float pr[8];
#pragma unroll
    for (int o = 0; o < 8; ++o) pr[o] = cs * w2r[o];
#pragma unroll
    for (int mk = 1; mk < 64; mk <<= 1)
#pragma unroll
        for (int o = 0; o < 8; ++o) pr[o] += __shfl_xor(pr[o], mk);
    if (lane == 0)
#pragma unroll
        for (int o = 0; o < 8; ++o) lm[wid][o] = pr[o];

    float v2 = 0.f;
    const float* v = state + (size_t)(B + b) * D;
#pragma unroll
    for (int j = 0; j < D / H; ++j) { float vv = v[j * H + h]; v2 += vv * vv; }
#pragma unroll
    for (int mk = 1; mk < 64; mk <<= 1) v2 += __shfl_xor(v2, mk);
    if (lane == 0) lv[wid] = v2;
    __syncthreads();

    if (tid < 8) {
        float a = 0.f;
        for (int w = 0; w < 8; ++w) a += lm[w][tid];
        ms[tid] = a;
    }
    if (tid == 0) {
        float a = 0.f;
        for (int w = 0; w < 8; ++w) a += lv[w];
        ws[OFF_VN + b] = sqrtf(a) + 1e-6f;
    }
    __syncthreads();

    float q = 0.f;
#pragma unroll
    for (int o = 0; o < 8; ++o) q += w2r[o] * ms[o];
    sQ[h] = q;
    __syncthreads();

    // ---- phase B: one (n,b) per wave per iteration ----
    unsigned short* __restrict__ WHp = (unsigned short*)(ws + OFF_WH);
    unsigned short* __restrict__ WLp = (unsigned short*)(ws + OFF_WL);

    for (int it = 0; it < 8; ++it) {
        int n = it * 8 + wid;
        float M[8];
#pragma unroll
        for (int o = 0; o < 8; ++o) M[o] = 0.f;
#pragma unroll
        for (int j = 0; j < 8; ++j) {
            int hh = j * 64 + lane;
            float ps = ws[OFF_P + n * H + hh] * sS[hh];
            const float4* wp = (const float4*)(W2 + hh * 8);
            float4 wa = wp[0], wb = wp[1];
            M[0] += ps * wa.x; M[1] += ps * wa.y; M[2] += ps * wa.z; M[3] += ps * wa.w;
            M[4] += ps * wb.x; M[5] += ps * wb.y; M[6] += ps * wb.z; M[7] += ps * wb.w;
        }
#pragma unroll
        for (int mk = 1; mk < 64; mk <<= 1)
#pragma unroll
            for (int o = 0; o < 8; ++o) M[o] += __shfl_xor(M[o], mk);

#pragma unroll
        for (int j = 0; j < 8; ++j) {
            int hh = j * 64 + lane;
            const float4* wp = (const float4*)(W2 + hh * 8);
            float4 wa = wp[0], wb = wp[1];
            float r = wa.x*M[0] + wa.y*M[1] + wa.z*M[2] + wa.w*M[3]
                    + wb.x*M[4] + wb.y*M[5] + wb.z*M[6] + wb.w*M[7];
            float P = ws[OFF_P + n * H + hh];
            float wval = sS2[hh] * (P * sQ[hh] + sC[hh] * r);
            unsigned short hi = f2bf(wval);
            WHp[(b * NCH + n) * H + hh] = hi;
            WLp[(b * NCH + n) * H + hh] = f2bf(wval - bf2f(hi));
        }
    }
}

// K4: 256 blocks x 512 thr; 2 (i,b)-units per block (shared i => shared W1 reads);
// per unit 4 waves split K; named register double-buffer; LDS cross-wave reduce;
// fused norm/y/z epilogue.
__global__ __launch_bounds__(512, 2) void k4_mfma(const float* __restrict__ state,
                                                  float* __restrict__ ws) {
    int bid  = blockIdx.x;        // 0..255
    int tid  = threadIdx.x;       // 0..511
    int g    = tid >> 8;          // unit within block
    int gt   = tid & 255;
    int u    = bid * 2 + g;
    int i    = u >> 3, b = u & 7; // both units share i
    int wvid = gt >> 6;
    int lane = tid & 63;
    int r16  = lane & 15;
    int kgrp = (lane >> 4) * 8;

    __shared__ float gp[2][2][64][67];
    __shared__ float coefs[2][64];

    const unsigned short* __restrict__ W1Hp = (const unsigned short*)(ws + OFF_W1H);
    const unsigned short* __restrict__ W1Lp = (const unsigned short*)(ws + OFF_W1L);
    const unsigned short* __restrict__ WHp  = (const unsigned short*)(ws + OFF_WH);
    const unsigned short* __restrict__ WLp  = (const unsigned short*)(ws + OFF_WL);

    f32x4 acc[4][4];
    f32x4 zz = {0.f, 0.f, 0.f, 0.f};
#pragma unroll
    for (int m = 0; m < 4; ++m)
#pragma unroll
        for (int c = 0; c < 4; ++c) acc[m][c] = zz;

    int kb    = wvid * 128 + kgrp;
    int baseA = (b * 64 + r16) * H;
    int baseB = (i * 64 + r16) * H;

    bf16x8 A0[8], B0[8], A1[8], B1[8];

#define LOADF(FA, FB, KOFS) do {                                           \
        int k_ = (KOFS);                                                   \
        _Pragma("unroll")                                                  \
        for (int m_ = 0; m_ < 4; ++m_) {                                   \
            int oA = baseA + m_ * 16 * H + k_;                             \
            FA[m_]     = *(const bf16x8*)(WHp + oA);                       \
            FA[4 + m_] = *(const bf16x8*)(WLp + oA);                       \
            int oB = baseB + m_ * 16 * H + k_;                             \
            FB[m_]     = *(const bf16x8*)(W1Hp + oB);                      \
            FB[4 + m_] = *(const bf16x8*)(W1Lp + oB);                      \
        } } while (0)

#define MFMA12(FA, FB) do {                                                \
        _Pragma("unroll")                                                  \
        for (int m = 0; m < 4; ++m)                                        \
        _Pragma("unroll")                                                  \
        for (int c = 0; c < 4; ++c) {                                      \
            acc[m][c] = __builtin_amdgcn_mfma_f32_16x16x32_bf16(FA[m], FB[c], acc[m][c], 0, 0, 0);       \
            acc[m][c] = __builtin_amdgcn_mfma_f32_16x16x32_bf16(FA[m], FB[4 + c], acc[m][c], 0, 0, 0);   \
            acc[m][c] = __builtin_amdgcn_mfma_f32_16x16x32_bf16(FA[4 + m], FB[c], acc[m][c], 0, 0, 0);   \
        } } while (0)

    LOADF(A0, B0, kb);
    LOADF(A1, B1, kb + 32);
    MFMA12(A0, B0);
    LOADF(A0, B0, kb + 64);
    MFMA12(A1, B1);
    LOADF(A1, B1, kb + 96);
    MFMA12(A0, B0);
    MFMA12(A1, B1);

#undef LOADF
#undef MFMA12

    // cross-wave K reduction within unit
    int rowb = (lane >> 4) * 4;
    if (wvid < 2) {
        float (*gpp)[67] = gp[g][wvid];
#pragma unroll
        for (int m = 0; m < 4; ++m)
#pragma unroll
            for (int c = 0; c < 4; ++c)
#pragma unroll
                for (int e = 0; e < 4; ++e)
                    gpp[m * 16 + rowb + e][c * 16 + r16] = acc[m][c][e];
    }
    __syncthreads();
    if (wvid >= 2) {
        float (*gpp)[67] = gp[g][wvid - 2];
#pragma unroll
        for (int m = 0; m < 4; ++m)
#pragma unroll
            for (int c = 0; c < 4; ++c)
#pragma unroll
                for (int e = 0; e < 4; ++e)
                    gpp[m * 16 + rowb + e][c * 16 + r16] += acc[m][c][e];
    }
    __syncthreads();

    const float* v = state + (size_t)(B + b) * D;
    if (gt < 64) {
        int n = gt;
        float ss = 0.f, y = 0.f;
#pragma unroll 8
        for (int k = 0; k < 64; ++k) {
            float gv = gp[g][0][n][k] + gp[g][1][n][k];
            ss += gv * gv;
            y  += gv * v[n * 64 + k];
        }
        float nrm = sqrtf(ss) + 1e-6f;
        ws[OFF_A1 + (size_t)(b * NCH + n) * CCH + i] = y / nrm;
        coefs[g][n] = v[n * 64 + i] / nrm;
    }
    __syncthreads();

    float* zb = ws + OFF_ZB + ((size_t)b * 64 + i) * 4096;
#pragma unroll
    for (int r = 0; r < 16; ++r) {
        int idx = gt + r * 256;
        int n = idx >> 6, k = idx & 63;
        zb[idx] = (gp[g][0][n][k] + gp[g][1][n][k]) * coefs[g][n];
    }
}

// K5: reduce z partials over i, final assembly
__global__ void k5_final(const float* __restrict__ state,
                         const float* __restrict__ ws,
                         float* __restrict__ out) {
    int idx = blockIdx.x * 512 + threadIdx.x;   // 0..32767
    float vel = state[32768 + idx];
    out[idx] = vel;
    int b = idx >> 12, e = idx & 4095;
    const float* zb = ws + OFF_ZB + (size_t)b * 64 * 4096 + e;
    float z = 0.f;
#pragma unroll 8
    for (int i = 0; i < 64; ++i) z += zb[(size_t)i * 4096];
    float a1 = ws[OFF_A1 + (size_t)b * 4096 + e];
    float av = -0.5f * vel * (a1 + z) / ws[OFF_VN + b];
    out[32768 + idx] = av - 0.1f * state[idx];
}

extern "C" void kernel_launch(void* const* d_in, const int* in_sizes, int n_in,
                              void* d_out, int out_size, void* d_ws, size_t ws_size,
                              hipStream_t stream) {
    const float* t   = (const float*)d_in[0];
    const float* st  = (const float*)d_in[1];
    const float* x0  = (const float*)d_in[2];
    const float* x1  = (const float*)d_in[3];
    const float* W1  = (const float*)d_in[4];
    const float* W2  = (const float*)d_in[5];
    float* out = (float*)d_out;
    float* ws  = (float*)d_ws;

    hipLaunchKernelGGL(k1_reduce_w1, dim3(64, 4), dim3(256), 0, stream, W1, st, x0, x1, t, ws);
    hipLaunchKernelGGL(k23,          dim3(8),     dim3(512), 0, stream, W2, st, ws);
    hipLaunchKernelGGL(k4_mfma,      dim3(256),   dim3(512), 0, stream, st, ws);
    hipLaunchKernelGGL(k5_final,     dim3(64),    dim3(512), 0, stream, st, ws, out);
}

// Round 6
// 117.817 us; speedup vs baseline: 2.1522x; 1.2987x over previous
//
#include <hip/hip_runtime.h>

#define D 4096
#define H 512
#define NCH 64
#define CCH 64
#define B 8

typedef __bf16 bf16x8 __attribute__((ext_vector_type(8)));
typedef float  f32x4  __attribute__((ext_vector_type(4)));

// workspace layout (float offsets)
#define OFF_P    0                         // P_nh[n][h]           32768
#define OFF_PHN  (OFF_P + NCH*H)           // P_hn[h][n]           32768
#define OFF_UPT  (OFF_PHN + H*NCH)         // up_t[b][h][n]        262144
#define OFF_S    (OFF_UPT + B*H*NCH)       // s[b][h]              4096
#define OFF_ST2  (OFF_S + B*H)             // -2*t*s[b][h]         4096
#define OFF_C    (OFF_ST2 + B*H)           // c[h]                 512
#define OFF_MS   (OFF_C + H)               // msum[b][o]           64   (atomic)
#define OFF_VN2  (OFF_MS + 64)             // ||v_b||^2            16   (atomic, pad)
#define OFF_A1   (OFF_VN2 + 16)            // a1[b][n*64+i]        32768
#define OFF_ZB   (OFF_A1 + B*NCH*CCH)      // zblk[b][i][n*64+k]   2097152
#define OFF_W1H  (OFF_ZB + B*64*4096)      // W1hi bf16 [d][h]
#define OFF_W1L  (OFF_W1H + (D*H)/2)       // W1lo bf16 [d][h]
#define OFF_WH   (OFF_W1L + (D*H)/2)       // whi bf16 [b][n][h]
#define OFF_WL   (OFF_WH + (B*NCH*H)/2)    // wlo bf16 [b][n][h]

__device__ __forceinline__ unsigned short f2bf(float x) {
    unsigned int u = __float_as_uint(x);
    unsigned int r = (u + 0x7FFFu + ((u >> 16) & 1u)) >> 16;   // RNE
    return (unsigned short)r;
}
__device__ __forceinline__ float bf2f(unsigned short s) {
    return __uint_as_float(((unsigned int)s) << 16);
}

// K1: per (n-chunk, h-quarter): float4 over h, j split 8 ways across threads.
// Produces: W1 bf16 hi/lo, P in both layouts, up_t[b][h][n]. Block (0,0) also
// zeroes the atomic accumulators used by K2 (stream order => visible to K2).
__global__ __launch_bounds__(256) void k1_reduce_w1(const float* __restrict__ W1,
                                                    const float* __restrict__ state,
                                                    const float* __restrict__ x0,
                                                    const float* __restrict__ x1,
                                                    const float* __restrict__ tptr,
                                                    float* __restrict__ ws) {
    int n   = blockIdx.x;              // 0..63
    int ht  = blockIdx.y;              // 0..3
    int tid = threadIdx.x;             // 0..255
    int hq  = ht * 32 + (tid & 31);    // float4 group of h: 0..127
    int jh  = tid >> 5;                // 0..7 (j-eighth)

    __shared__ float xs[B][64];
    __shared__ f32x4 red[8][32][9];    // [jh][lane][p,up0..up7]

    if (n == 0 && ht == 0 && tid < 80) ws[OFF_MS + tid] = 0.f;  // MS(64)+VN2(16)

    float ts = tptr[0];
    float window = 4.f * ts * (1.f - ts);
    if (tid < 64) {
        int d = n * 64 + tid;
        for (int b = 0; b < B; ++b) {
            float a0 = x0[b * D + d];
            float a1v = x1[b * D + d];
            float dev = state[b * D + d];
            xs[b][tid] = a0 + ts * (a1v - a0) + window * dev;
        }
    }
    __syncthreads();

    unsigned short* __restrict__ W1Hp = (unsigned short*)(ws + OFF_W1H);
    unsigned short* __restrict__ W1Lp = (unsigned short*)(ws + OFF_W1L);

    f32x4 p4 = {0.f, 0.f, 0.f, 0.f};
    f32x4 up[B];
#pragma unroll
    for (int b = 0; b < B; ++b) up[b] = p4;

#pragma unroll
    for (int jj = 0; jj < 8; ++jj) {
        int j = jh * 8 + jj;
        int d = n * 64 + j;
        f32x4 w = ((const f32x4*)W1)[d * (H / 4) + hq];
        p4 += w;
#pragma unroll
        for (int b = 0; b < B; ++b) up[b] += w * xs[b][j];
        unsigned short h0 = f2bf(w.x), h1 = f2bf(w.y), h2 = f2bf(w.z), h3 = f2bf(w.w);
        ushort4 hv = {h0, h1, h2, h3};
        ushort4 lv = {f2bf(w.x - bf2f(h0)), f2bf(w.y - bf2f(h1)),
                      f2bf(w.z - bf2f(h2)), f2bf(w.w - bf2f(h3))};
        *(ushort4*)(W1Hp + d * H + hq * 4) = hv;
        *(ushort4*)(W1Lp + d * H + hq * 4) = lv;
    }

    int l = tid & 31;
    red[jh][l][0] = p4;
#pragma unroll
    for (int b = 0; b < B; ++b) red[jh][l][1 + b] = up[b];
    __syncthreads();

    if (jh == 0) {
        f32x4 pt = red[0][l][0];
        f32x4 ut[B];
#pragma unroll
        for (int b = 0; b < B; ++b) ut[b] = red[0][l][1 + b];
        for (int g = 1; g < 8; ++g) {
            pt += red[g][l][0];
#pragma unroll
            for (int b = 0; b < B; ++b) ut[b] += red[g][l][1 + b];
        }
        *(f32x4*)(ws + OFF_P + n * H + hq * 4) = pt;
#pragma unroll
        for (int e = 0; e < 4; ++e) ws[OFF_PHN + (hq * 4 + e) * NCH + n] = pt[e];
#pragma unroll
        for (int b = 0; b < B; ++b)
#pragma unroll
            for (int e = 0; e < 4; ++e)
                ws[OFF_UPT + (b * H + hq * 4 + e) * NCH + n] = ut[b][e];
    }
}

// K2: 64 blocks (hs, b) x 512 thr. Per h: 8-lane group reduces u,c; computes
// s, st2; block-partials of msum[b][o] and ||v||^2 via one atomicAdd each.
__global__ __launch_bounds__(512) void k2_sample(const float* __restrict__ W2,
                                                 const float* __restrict__ state,
                                                 float* __restrict__ ws) {
    int hs = blockIdx.x;          // 0..7 h-slice
    int b  = blockIdx.y;          // 0..7
    int tid = threadIdx.x;        // 0..511
    int hl  = tid >> 3;           // 0..63
    int jg  = tid & 7;            // 0..7
    int h   = hs * 64 + hl;
    int wv  = tid >> 6, ln = tid & 63;

    __shared__ float msp[8][8];
    __shared__ float lvp[8];

    // u, c: 8 contiguous partials per lane, butterfly over the 8-lane group
    const float* up = ws + OFF_UPT + (size_t)(b * H + h) * NCH + jg * 8;
    const float* pc = ws + OFF_PHN + (size_t)h * NCH + jg * 8;
    f32x4 ua = *(const f32x4*)up, ub = *(const f32x4*)(up + 4);
    f32x4 ca = *(const f32x4*)pc, cb = *(const f32x4*)(pc + 4);
    float u = ua.x+ua.y+ua.z+ua.w + ub.x+ub.y+ub.z+ub.w;
    float c = ca.x+ca.y+ca.z+ca.w + cb.x+cb.y+cb.z+cb.w;
    u += __shfl_xor(u, 1); u += __shfl_xor(u, 2); u += __shfl_xor(u, 4);
    c += __shfl_xor(c, 1); c += __shfl_xor(c, 2); c += __shfl_xor(c, 4);

    float tt  = tanhf(u);
    float s   = 1.f - tt * tt;
    float st2 = -2.f * tt * s;
    if (jg == 0) {
        ws[OFF_S   + b * H + h] = s;
        ws[OFF_ST2 + b * H + h] = st2;
        ws[OFF_C   + h] = c;          // b-redundant identical value — benign
    }

    // msum partial: lane jg handles o=jg for its h; W2 access is coalesced
    float mv = c * s * W2[hs * 512 + tid];
    mv += __shfl_xor(mv, 8); mv += __shfl_xor(mv, 16); mv += __shfl_xor(mv, 32);
    if (ln < 8) msp[wv][ln] = mv;

    // ||v||^2 partial: this block covers d-slice [hs*512, hs*512+512)
    float vv = state[(size_t)(B + b) * D + hs * 512 + tid];
    float v2 = vv * vv;
#pragma unroll
    for (int mk = 1; mk < 64; mk <<= 1) v2 += __shfl_xor(v2, mk);
    if (ln == 0) lvp[wv] = v2;
    __syncthreads();

    if (tid < 8) {
        float a = 0.f;
#pragma unroll
        for (int w = 0; w < 8; ++w) a += msp[w][tid];
        atomicAdd(&ws[OFF_MS + b * 8 + tid], a);
    }
    if (tid == 8) {
        float a = 0.f;
#pragma unroll
        for (int w = 0; w < 8; ++w) a += lvp[w];
        atomicAdd(&ws[OFF_VN2 + b], a);
    }
}

// K3: 512 blocks (n,b) x 64 thr: M-reduce, r, q on-the-fly, w -> bf16 hi/lo
__global__ void k3_w(const float* __restrict__ W2,
                     float* __restrict__ ws) {
    int n = blockIdx.x, b = blockIdx.y, lane = threadIdx.x;   // 64 threads
    float msv[8];
#pragma unroll
    for (int o = 0; o < 8; ++o) msv[o] = ws[OFF_MS + b * 8 + o];

    float M[8];
#pragma unroll
    for (int o = 0; o < 8; ++o) M[o] = 0.f;
#pragma unroll
    for (int j = 0; j < 8; ++j) {
        int h = j * 64 + lane;
        float ps = ws[OFF_P + n * H + h] * ws[OFF_S + b * H + h];
        const float4* wp = (const float4*)(W2 + h * 8);
        float4 wa = wp[0], wb = wp[1];
        M[0] += ps * wa.x; M[1] += ps * wa.y; M[2] += ps * wa.z; M[3] += ps * wa.w;
        M[4] += ps * wb.x; M[5] += ps * wb.y; M[6] += ps * wb.z; M[7] += ps * wb.w;
    }
#pragma unroll
    for (int mk = 1; mk < 64; mk <<= 1)
#pragma unroll
        for (int o = 0; o < 8; ++o) M[o] += __shfl_xor(M[o], mk);

    unsigned short* __restrict__ WHp = (unsigned short*)(ws + OFF_WH);
    unsigned short* __restrict__ WLp = (unsigned short*)(ws + OFF_WL);
#pragma unroll
    for (int j = 0; j < 8; ++j) {
        int h = j * 64 + lane;
        const float4* wp = (const float4*)(W2 + h * 8);
        float4 wa = wp[0], wb = wp[1];
        float r = wa.x*M[0] + wa.y*M[1] + wa.z*M[2] + wa.w*M[3]
                + wb.x*M[4] + wb.y*M[5] + wb.z*M[6] + wb.w*M[7];
        float q = wa.x*msv[0] + wa.y*msv[1] + wa.z*msv[2] + wa.w*msv[3]
                + wb.x*msv[4] + wb.y*msv[5] + wb.z*msv[6] + wb.w*msv[7];
        float P = ws[OFF_P + n * H + h];
        float wval = ws[OFF_ST2 + b * H + h] * (P * q + ws[OFF_C + h] * r);
        unsigned short hi = f2bf(wval);
        WHp[(b * NCH + n) * H + h] = hi;
        WLp[(b * NCH + n) * H + h] = f2bf(wval - bf2f(hi));
    }
}

// K4: 256 blocks x 512 thr; 2 (i,b)-units per block (shared i => shared W1 reads);
// per unit 4 waves split K; named register double-buffer; LDS cross-wave reduce;
// fused norm/y/z epilogue.
__global__ __launch_bounds__(512, 2) void k4_mfma(const float* __restrict__ state,
                                                  float* __restrict__ ws) {
    int bid  = blockIdx.x;        // 0..255
    int tid  = threadIdx.x;       // 0..511
    int g    = tid >> 8;          // unit within block
    int gt   = tid & 255;
    int u    = bid * 2 + g;
    int i    = u >> 3, b = u & 7; // both units share i
    int wvid = gt >> 6;
    int lane = tid & 63;
    int r16  = lane & 15;
    int kgrp = (lane >> 4) * 8;

    __shared__ float gp[2][2][64][67];
    __shared__ float coefs[2][64];

    const unsigned short* __restrict__ W1Hp = (const unsigned short*)(ws + OFF_W1H);
    const unsigned short* __restrict__ W1Lp = (const unsigned short*)(ws + OFF_W1L);
    const unsigned short* __restrict__ WHp  = (const unsigned short*)(ws + OFF_WH);
    const unsigned short* __restrict__ WLp  = (const unsigned short*)(ws + OFF_WL);

    f32x4 acc[4][4];
    f32x4 zz = {0.f, 0.f, 0.f, 0.f};
#pragma unroll
    for (int m = 0; m < 4; ++m)
#pragma unroll
        for (int c = 0; c < 4; ++c) acc[m][c] = zz;

    int kb    = wvid * 128 + kgrp;
    int baseA = (b * 64 + r16) * H;
    int baseB = (i * 64 + r16) * H;

    bf16x8 A0[8], B0[8], A1[8], B1[8];

#define LOADF(FA, FB, KOFS) do {                                           \
        int k_ = (KOFS);                                                   \
        _Pragma("unroll")                                                  \
        for (int m_ = 0; m_ < 4; ++m_) {                                   \
            int oA = baseA + m_ * 16 * H + k_;                             \
            FA[m_]     = *(const bf16x8*)(WHp + oA);                       \
            FA[4 + m_] = *(const bf16x8*)(WLp + oA);                       \
            int oB = baseB + m_ * 16 * H + k_;                             \
            FB[m_]     = *(const bf16x8*)(W1Hp + oB);                      \
            FB[4 + m_] = *(const bf16x8*)(W1Lp + oB);                      \
        } } while (0)

#define MFMA12(FA, FB) do {                                                \
        _Pragma("unroll")                                                  \
        for (int m = 0; m < 4; ++m)                                        \
        _Pragma("unroll")                                                  \
        for (int c = 0; c < 4; ++c) {                                      \
            acc[m][c] = __builtin_amdgcn_mfma_f32_16x16x32_bf16(FA[m], FB[c], acc[m][c], 0, 0, 0);       \
            acc[m][c] = __builtin_amdgcn_mfma_f32_16x16x32_bf16(FA[m], FB[4 + c], acc[m][c], 0, 0, 0);   \
            acc[m][c] = __builtin_amdgcn_mfma_f32_16x16x32_bf16(FA[4 + m], FB[c], acc[m][c], 0, 0, 0);   \
        } } while (0)

    LOADF(A0, B0, kb);
    LOADF(A1, B1, kb + 32);
    MFMA12(A0, B0);
    LOADF(A0, B0, kb + 64);
    MFMA12(A1, B1);
    LOADF(A1, B1, kb + 96);
    MFMA12(A0, B0);
    MFMA12(A1, B1);

#undef LOADF
#undef MFMA12

    // cross-wave K reduction within unit
    int rowb = (lane >> 4) * 4;
    if (wvid < 2) {
        float (*gpp)[67] = gp[g][wvid];
#pragma unroll
        for (int m = 0; m < 4; ++m)
#pragma unroll
            for (int c = 0; c < 4; ++c)
#pragma unroll
                for (int e = 0; e < 4; ++e)
                    gpp[m * 16 + rowb + e][c * 16 + r16] = acc[m][c][e];
    }
    __syncthreads();
    if (wvid >= 2) {
        float (*gpp)[67] = gp[g][wvid - 2];
#pragma unroll
        for (int m = 0; m < 4; ++m)
#pragma unroll
            for (int c = 0; c < 4; ++c)
#pragma unroll
                for (int e = 0; e < 4; ++e)
                    gpp[m * 16 + rowb + e][c * 16 + r16] += acc[m][c][e];
    }
    __syncthreads();

    const float* v = state + (size_t)(B + b) * D;
    if (gt < 64) {
        int n = gt;
        float ss = 0.f, y = 0.f;
#pragma unroll 8
        for (int k = 0; k < 64; ++k) {
            float gv = gp[g][0][n][k] + gp[g][1][n][k];
            ss += gv * gv;
            y  += gv * v[n * 64 + k];
        }
        float nrm = sqrtf(ss) + 1e-6f;
        ws[OFF_A1 + (size_t)(b * NCH + n) * CCH + i] = y / nrm;
        coefs[g][n] = v[n * 64 + i] / nrm;
    }
    __syncthreads();

    float* zb = ws + OFF_ZB + ((size_t)b * 64 + i) * 4096;
#pragma unroll
    for (int r = 0; r < 16; ++r) {
        int idx = gt + r * 256;
        int n = idx >> 6, k = idx & 63;
        zb[idx] = (gp[g][0][n][k] + gp[g][1][n][k]) * coefs[g][n];
    }
}

// K5: reduce z partials over i, final assembly
__global__ void k5_final(const float* __restrict__ state,
                         const float* __restrict__ ws,
                         float* __restrict__ out) {
    int idx = blockIdx.x * 512 + threadIdx.x;   // 0..32767
    float vel = state[32768 + idx];
    out[idx] = vel;
    int b = idx >> 12, e = idx & 4095;
    const float* zb = ws + OFF_ZB + (size_t)b * 64 * 4096 + e;
    float z = 0.f;
#pragma unroll 8
    for (int i = 0; i < 64; ++i) z += zb[(size_t)i * 4096];
    float a1 = ws[OFF_A1 + (size_t)b * 4096 + e];
    float vn = sqrtf(ws[OFF_VN2 + b]) + 1e-6f;
    float av = -0.5f * vel * (a1 + z) / vn;
    out[32768 + idx] = av - 0.1f * state[idx];
}

extern "C" void kernel_launch(void* const* d_in, const int* in_sizes, int n_in,
                              void* d_out, int out_size, void* d_ws, size_t ws_size,
                              hipStream_t stream) {
    const float* t   = (const float*)d_in[0];
    const float* st  = (const float*)d_in[1];
    const float* x0  = (const float*)d_in[2];
    const float* x1  = (const float*)d_in[3];
    const float* W1  = (const float*)d_in[4];
    const float* W2  = (const float*)d_in[5];
    float* out = (float*)d_out;
    float* ws  = (float*)d_ws;

    hipLaunchKernelGGL(k1_reduce_w1, dim3(64, 4), dim3(256), 0, stream, W1, st, x0, x1, t, ws);
    hipLaunchKernelGGL(k2_sample,    dim3(8, 8),  dim3(512), 0, stream, W2, st, ws);
    hipLaunchKernelGGL(k3_w,         dim3(64, 8), dim3(64),  0, stream, W2, ws);
    hipLaunchKernelGGL(k4_mfma,      dim3(256),   dim3(512), 0, stream, st, ws);
    hipLaunchKernelGGL(k5_final,     dim3(64),    dim3(512), 0, stream, st, ws, out);
}